// Round 3
// baseline (1432.486 us; speedup 1.0000x reference)
//
#include <hip/hip_runtime.h>

// Problem constants (from reference)
#define Bb   4
#define Ts   512
#define Hh   2048
#define Vv   32000
#define Nn   2048            // B*T
#define BETA 0.1f

// Tiling: each block owns 128 rows x 256 cols (2 v-tiles of 128), one K-loop
// per pass with A-tile shared across both v-tiles (64 MFMAs per barrier-pair).
#define CHUNKS 125           // 125 * 256 = 32000 = V
#define NPC    250           // partial sets = CHUNKS * 2 (one per wave-column half)

typedef _Float16 h8  __attribute__((ext_vector_type(8)));
typedef _Float16 h4v __attribute__((ext_vector_type(4)));
typedef float    f4  __attribute__((ext_vector_type(4)));

// LDS tiles: [128 rows][64 halfs] each, XOR-swizzled so stride-128B ds_read_b128
// column reads spread across banks (G4). XOR term touches half-index bits 3..5
// only -> 16B/8B groups stay aligned.
__device__ __forceinline__ int swz(int row, int k) {
    return row * 64 + (k ^ ((row & 7) << 3));
}

template<bool FAST>
__global__ __launch_bounds__(256, 2) void grpo_gemm(
    const float* __restrict__ inP, const float* __restrict__ wP, const float* __restrict__ bP,
    const float* __restrict__ inR, const float* __restrict__ wR, const float* __restrict__ bR,
    const _Float16* __restrict__ inP16, const _Float16* __restrict__ wP16,
    const _Float16* __restrict__ inR16, const _Float16* __restrict__ wR16,
    float* __restrict__ Pm, float* __restrict__ Ps, int* __restrict__ Pa,
    float* __restrict__ Rm, float* __restrict__ Rs, float* __restrict__ Ra)
{
    // A at [0,8192), W0 at [8192,16384), W1 at [16384,24576)  (halfs) = 48 KB
    __shared__ __align__(16) unsigned short lds[24576];

    const int rowT  = blockIdx.x;           // 0..15
    const int chunk = blockIdx.y;           // 0..124
    const int tid   = threadIdx.x;
    const int lane  = tid & 63;
    const int wid   = tid >> 6;
    const int wr    = wid >> 1;             // wave row half (0/1)
    const int wc    = wid & 1;              // wave col half (0/1)
    const int lr    = lane & 15;
    const int lk    = lane >> 4;

    const int rowBase = rowT * 128;
    const int colBase = chunk * 256;

    f4 acc[2][4][4];                        // [vtile][m][n], all statically indexed

    // 64 MFMAs from the staged LDS tiles (one kt step)
    auto mma_all = [&]() {
        #pragma unroll
        for (int ks = 0; ks < 2; ++ks) {
            h8 af[4];
            #pragma unroll
            for (int m = 0; m < 4; m++)
                af[m] = *reinterpret_cast<const h8*>(&lds[swz(wr * 64 + m * 16 + lr, ks * 32 + lk * 8)]);
            #pragma unroll
            for (int vt = 0; vt < 2; ++vt) {
                h8 wf[4];
                #pragma unroll
                for (int n = 0; n < 4; n++)
                    wf[n] = *reinterpret_cast<const h8*>(
                        &lds[8192 + vt * 8192 + swz(wc * 64 + n * 16 + lr, ks * 32 + lk * 8)]);
                #pragma unroll
                for (int m = 0; m < 4; m++)
                    #pragma unroll
                    for (int n = 0; n < 4; n++)
                        acc[vt][m][n] = __builtin_amdgcn_mfma_f32_16x16x32_f16(af[m], wf[n], acc[vt][m][n], 0, 0, 0);
            }
        }
    };

    // ---- one full pass (policy or ref): 128x256 logits into acc ----
    auto pass_gemm = [&](const float* __restrict__ IN, const float* __restrict__ W,
                         const _Float16* __restrict__ IN16, const _Float16* __restrict__ W16) {
        #pragma unroll
        for (int vt = 0; vt < 2; ++vt)
            #pragma unroll
            for (int m = 0; m < 4; m++)
                #pragma unroll
                for (int n = 0; n < 4; n++) { f4 z = {0.f, 0.f, 0.f, 0.f}; acc[vt][m][n] = z; }

        if constexpr (FAST) {
            // global_load_lds: LDS dest = wave-uniform base + lane*16 (linear).
            // Global source is pre-(inverse-)swizzled: the same involution the
            // swizzled ds_read applies (rule 21: both-sides-or-neither).
            const int rsub = lane >> 3;                       // row within 8-row chunk
            const int ksrc = ((lane & 7) ^ rsub) << 3;        // pre-swizzled k (halfs)
            const _Float16* aSrc[4]; const _Float16* w0Src[4]; const _Float16* w1Src[4];
            #pragma unroll
            for (int i = 0; i < 4; i++) {
                const int c = wid * 4 + i;                    // 1KB chunk id, wave-uniform
                const int r = c * 8 + rsub;                   // tile row 0..127
                aSrc[i]  = IN16 + (size_t)(rowBase + r) * Hh + ksrc;
                w0Src[i] = W16  + (size_t)(colBase + r) * Hh + ksrc;
                w1Src[i] = W16  + (size_t)(colBase + 128 + r) * Hh + ksrc;
            }
            for (int kt = 0; kt < Hh / 64; ++kt) {
                __syncthreads();               // previous iteration's reads done
                #pragma unroll
                for (int i = 0; i < 4; i++) {
                    const int c = wid * 4 + i;
                    __builtin_amdgcn_global_load_lds(
                        (const __attribute__((address_space(1))) void*)(aSrc[i] + kt * 64),
                        (__attribute__((address_space(3))) void*)&lds[c * 512], 16, 0, 0);
                    __builtin_amdgcn_global_load_lds(
                        (const __attribute__((address_space(1))) void*)(w0Src[i] + kt * 64),
                        (__attribute__((address_space(3))) void*)&lds[8192 + c * 512], 16, 0, 0);
                    __builtin_amdgcn_global_load_lds(
                        (const __attribute__((address_space(1))) void*)(w1Src[i] + kt * 64),
                        (__attribute__((address_space(3))) void*)&lds[16384 + c * 512], 16, 0, 0);
                }
                __syncthreads();               // barrier drains vmcnt -> LDS ready
                mma_all();
            }
        } else {
            const float* Ab = IN + (size_t)rowBase * Hh;
            const float* Wb = W  + (size_t)colBase * Hh;
            for (int kt = 0; kt < Hh / 64; ++kt) {
                __syncthreads();
                #pragma unroll
                for (int i = 0; i < 8; i++) {   // stage A tile (128x64 fp32 -> f16)
                    int f = tid + i * 256;
                    int r = f >> 4, kk = (f & 15) << 2;
                    const float4 v = *reinterpret_cast<const float4*>(Ab + (size_t)r * Hh + kt * 64 + kk);
                    h4v h; h[0] = (_Float16)v.x; h[1] = (_Float16)v.y; h[2] = (_Float16)v.z; h[3] = (_Float16)v.w;
                    *reinterpret_cast<h4v*>(&lds[swz(r, kk)]) = h;
                }
                #pragma unroll
                for (int i = 0; i < 16; i++) {  // stage both W tiles (256x64 fp32 -> f16)
                    int f = tid + i * 256;
                    int vt = f >> 11, g = f & 2047;
                    int r = g >> 4, kk = (g & 15) << 2;
                    const float4 v = *reinterpret_cast<const float4*>(Wb + (size_t)(vt * 128 + r) * Hh + kt * 64 + kk);
                    h4v h; h[0] = (_Float16)v.x; h[1] = (_Float16)v.y; h[2] = (_Float16)v.z; h[3] = (_Float16)v.w;
                    *reinterpret_cast<h4v*>(&lds[8192 + vt * 8192 + swz(r, kk)]) = h;
                }
                __syncthreads();
                mma_all();
            }
        }
    };

    // ================= policy pass: online max/argmax/sumexp =================
    // C/D layout (m89-verified): col = lane&15, row = (lane>>4)*4 + reg.
    float sM[16], sS[16]; int sA[16];
    #pragma unroll
    for (int s = 0; s < 16; s++) { sM[s] = -__builtin_inff(); sS[s] = 0.f; sA[s] = 0x7fffffff; }

    pass_gemm(inP, wP, inP16, wP16);
    #pragma unroll
    for (int vt = 0; vt < 2; ++vt) {
        float bn[4];
        #pragma unroll
        for (int n = 0; n < 4; n++) bn[n] = bP[colBase + vt * 128 + wc * 64 + n * 16 + lr];
        #pragma unroll
        for (int m = 0; m < 4; m++)
            #pragma unroll
            for (int n = 0; n < 4; n++) {
                const int vg = colBase + vt * 128 + wc * 64 + n * 16 + lr;
                #pragma unroll
                for (int r = 0; r < 4; r++) {
                    const int s = m * 4 + r;
                    const float v = acc[vt][m][n][r] + bn[n];
                    if (v > sM[s]) { sS[s] = sS[s] * __expf(sM[s] - v) + 1.f; sM[s] = v; sA[s] = vg; }
                    else           { sS[s] += __expf(v - sM[s]); }
                }
            }
    }

    // 16-lane butterfly (merges the 16 lr columns; lk stays fixed -> same rows).
    int aWin[16];
    #pragma unroll
    for (int s = 0; s < 16; s++) {
        float M = sM[s], S = sS[s]; int A = sA[s];
        #pragma unroll
        for (int d = 1; d < 16; d <<= 1) {
            float oM = __shfl_xor(M, d), oS = __shfl_xor(S, d); int oA = __shfl_xor(A, d);
            if (oM > M || (oM == M && oA < A)) { S = S * __expf(M - oM) + oS; M = oM; A = oA; }
            else                               { S += oS * __expf(oM - M); }
        }
        aWin[s] = A;
        if (lr == 0) {
            const int row = rowBase + wr * 64 + (s >> 2) * 16 + lk * 4 + (s & 3);
            const size_t id = (size_t)(chunk * 2 + wc) * Nn + row;
            Pm[id] = M; Ps[id] = S; Pa[id] = A;
        }
    }

    // ================= ref pass: lse stats + ref logit at policy argmax =================
    float rM[16], rS[16], rT[16];
    #pragma unroll
    for (int s = 0; s < 16; s++) { rM[s] = -__builtin_inff(); rS[s] = 0.f; rT[s] = -1e30f; }

    pass_gemm(inR, wR, inR16, wR16);
    #pragma unroll
    for (int vt = 0; vt < 2; ++vt) {
        float bn[4];
        #pragma unroll
        for (int n = 0; n < 4; n++) bn[n] = bR[colBase + vt * 128 + wc * 64 + n * 16 + lr];
        #pragma unroll
        for (int m = 0; m < 4; m++)
            #pragma unroll
            for (int n = 0; n < 4; n++) {
                const int vg = colBase + vt * 128 + wc * 64 + n * 16 + lr;
                #pragma unroll
                for (int r = 0; r < 4; r++) {
                    const int s = m * 4 + r;
                    const float v = acc[vt][m][n][r] + bn[n];
                    if (v > rM[s]) { rS[s] = rS[s] * __expf(rM[s] - v) + 1.f; rM[s] = v; }
                    else           { rS[s] += __expf(v - rM[s]); }
                    if (vg == aWin[s]) rT[s] = v;   // ref logit at this chunk-half's policy argmax
                }
            }
    }

    #pragma unroll
    for (int s = 0; s < 16; s++) {
        float M = rM[s], S = rS[s], Tv = rT[s];
        #pragma unroll
        for (int d = 1; d < 16; d <<= 1) {
            float oM = __shfl_xor(M, d), oS = __shfl_xor(S, d), oT = __shfl_xor(Tv, d);
            if (oM > M) { S = S * __expf(M - oM) + oS; M = oM; }
            else        { S += oS * __expf(oM - M); }
            Tv = fmaxf(Tv, oT);
        }
        if (lr == 0) {
            const int row = rowBase + wr * 64 + (s >> 2) * 16 + lk * 4 + (s & 3);
            const size_t id = (size_t)(chunk * 2 + wc) * Nn + row;
            Rm[id] = M; Rs[id] = S; Ra[id] = Tv;
        }
    }
}

// fp32 -> f16 bulk convert (memory-bound, ~160us total for all four arrays)
__global__ __launch_bounds__(256) void cvt16(const float* __restrict__ s, _Float16* __restrict__ d, size_t n)
{
    size_t i = ((size_t)blockIdx.x * 256 + threadIdx.x) * 8;
    const size_t stride = (size_t)gridDim.x * 256 * 8;
    for (; i < n; i += stride) {
        const float4 a = *reinterpret_cast<const float4*>(s + i);
        const float4 b = *reinterpret_cast<const float4*>(s + i + 4);
        h8 h;
        h[0] = (_Float16)a.x; h[1] = (_Float16)a.y; h[2] = (_Float16)a.z; h[3] = (_Float16)a.w;
        h[4] = (_Float16)b.x; h[5] = (_Float16)b.y; h[6] = (_Float16)b.z; h[7] = (_Float16)b.w;
        *reinterpret_cast<h8*>(d + i) = h;
    }
}

// Merge NPC partials per row, compute per-token loss, block-reduce, atomicAdd num/den.
__global__ __launch_bounds__(256) void grpo_combine(
    const float* __restrict__ Pm, const float* __restrict__ Ps, const int* __restrict__ Pa,
    const float* __restrict__ Rm, const float* __restrict__ Rs, const float* __restrict__ Ra,
    const float* __restrict__ amask, const float* __restrict__ rewards,
    float* __restrict__ accv)
{
    const int row = blockIdx.x * 256 + threadIdx.x;   // 0..2047

    // group-normalized advantages (ddof=1, +EPS on std)
    const float r0 = rewards[0], r1 = rewards[1], r2 = rewards[2], r3 = rewards[3];
    const float mean = 0.25f * (r0 + r1 + r2 + r3);
    const float var  = ((r0 - mean) * (r0 - mean) + (r1 - mean) * (r1 - mean) +
                        (r2 - mean) * (r2 - mean) + (r3 - mean) * (r3 - mean)) * (1.f / 3.f);
    const float inv  = 1.f / (sqrtf(var) + 1e-4f);
    const int   b    = row >> 9;                      // row / T
    const float advb = (b == 0 ? (r0 - mean) : b == 1 ? (r1 - mean) : b == 2 ? (r2 - mean) : (r3 - mean)) * inv;

    // policy: lexicographic (max, idx) merge == jnp.argmax first-occurrence
    float M = -__builtin_inff(), S = 0.f; int A = 0x7fffffff, cwin = 0;
    for (int pc = 0; pc < NPC; ++pc) {
        const size_t id = (size_t)pc * Nn + row;
        const float m = Pm[id], s = Ps[id]; const int a = Pa[id];
        if (m > M || (m == M && a < A)) { S = S * expf(M - m) + s; M = m; A = a; cwin = pc; }
        else                            { S += s * expf(m - M); }
    }
    const float tok = -logf(S);                       // chosen == argmax -> tok_lp = -log(sumexp rel max)

    float RM = -__builtin_inff(), RS = 0.f;
    for (int pc = 0; pc < NPC; ++pc) {
        const size_t id = (size_t)pc * Nn + row;
        const float m = Rm[id], s = Rs[id];
        if (m > RM) { RS = RS * expf(RM - m) + s; RM = m; }
        else        { RS += s * expf(m - RM); }
    }
    const float rtok = Ra[(size_t)cwin * Nn + row] - (RM + logf(RS));

    const float d  = rtok - tok;
    const float kl = expf(d) - d - 1.f;
    const float mk = amask[row];
    // ratio = exp(tok - stop_grad(tok)) == 1 in fwd -> policy term = -adv
    const float num = (-advb + BETA * kl) * mk;

    __shared__ float rN[256], rD[256];
    rN[threadIdx.x] = num; rD[threadIdx.x] = mk;
    __syncthreads();
    for (int o = 128; o > 0; o >>= 1) {
        if (threadIdx.x < o) { rN[threadIdx.x] += rN[threadIdx.x + o]; rD[threadIdx.x] += rD[threadIdx.x + o]; }
        __syncthreads();
    }
    if (threadIdx.x == 0) { atomicAdd(&accv[0], rN[0]); atomicAdd(&accv[1], rD[0]); }
}

__global__ void grpo_final(const float* __restrict__ accv, float* __restrict__ out) {
    out[0] = accv[0] / fmaxf(accv[1], 1.f);
}

extern "C" void kernel_launch(void* const* d_in, const int* in_sizes, int n_in,
                              void* d_out, int out_size, void* d_ws, size_t ws_size,
                              hipStream_t stream)
{
    (void)in_sizes; (void)n_in; (void)out_size;

    const float* inP = (const float*)d_in[0];   // _input        [N,H]
    const float* wP  = (const float*)d_in[1];   // weight        [V,H]
    const float* am  = (const float*)d_in[2];   // attention_mask[B,T]
    const float* rw  = (const float*)d_in[3];   // rewards       [B]
    const float* bP  = (const float*)d_in[4];   // bias          [V]
    const float* inR = (const float*)d_in[5];   // ref_input     [N,H]
    const float* wR  = (const float*)d_in[6];   // ref_weight    [V,H]
    const float* bR  = (const float*)d_in[7];   // ref_bias      [V]
    float* out = (float*)d_out;

    // workspace layout: 6 partial arrays [NPC][N] + accv, then (if room) f16 copies
    char* w = (char*)d_ws;
    const size_t arr = (size_t)NPC * Nn * sizeof(float);    // 2,048,000 B (16B-aligned)
    float* Pm = (float*)w; w += arr;
    float* Ps = (float*)w; w += arr;
    int*   Pa = (int*)  w; w += arr;
    float* Rm = (float*)w; w += arr;
    float* Rs = (float*)w; w += arr;
    float* Ra = (float*)w; w += arr;
    float* accv = (float*)w; w += 256;                      // pad, keep 16B alignment

    const size_t fA = (size_t)Nn * Hh * sizeof(_Float16);   //   8,388,608 B
    const size_t fW = (size_t)Vv * Hh * sizeof(_Float16);   // 131,072,000 B
    const size_t need = (size_t)(w - (char*)d_ws) + 2 * fA + 2 * fW;   // ~291.5 MB
    const bool fast = (ws_size >= need);

    hipMemsetAsync(accv, 0, 2 * sizeof(float), stream);

    if (fast) {
        _Float16* inP16 = (_Float16*)w;            w += fA;
        _Float16* inR16 = (_Float16*)w;            w += fA;
        _Float16* wP16  = (_Float16*)w;            w += fW;
        _Float16* wR16  = (_Float16*)w;            w += fW;
        hipLaunchKernelGGL(cvt16, dim3(512),  dim3(256), 0, stream, inP, inP16, (size_t)Nn * Hh);
        hipLaunchKernelGGL(cvt16, dim3(512),  dim3(256), 0, stream, inR, inR16, (size_t)Nn * Hh);
        hipLaunchKernelGGL(cvt16, dim3(2048), dim3(256), 0, stream, wP,  wP16,  (size_t)Vv * Hh);
        hipLaunchKernelGGL(cvt16, dim3(2048), dim3(256), 0, stream, wR,  wR16,  (size_t)Vv * Hh);
        hipLaunchKernelGGL((grpo_gemm<true>), dim3(16, CHUNKS), dim3(256), 0, stream,
                           inP, wP, bP, inR, wR, bR, inP16, wP16, inR16, wR16,
                           Pm, Ps, Pa, Rm, Rs, Ra);
    } else {
        hipLaunchKernelGGL((grpo_gemm<false>), dim3(16, CHUNKS), dim3(256), 0, stream,
                           inP, wP, bP, inR, wR, bR,
                           (const _Float16*)nullptr, (const _Float16*)nullptr,
                           (const _Float16*)nullptr, (const _Float16*)nullptr,
                           Pm, Ps, Pa, Rm, Rs, Ra);
    }

    hipLaunchKernelGGL(grpo_combine, dim3(Nn / 256), dim3(256), 0, stream,
                       Pm, Ps, Pa, Rm, Rs, Ra, am, rw, accv);
    hipLaunchKernelGGL(grpo_final, dim3(1), dim3(1), 0, stream, accv, out);
}

// Round 4
// 1414.480 us; speedup vs baseline: 1.0127x; 1.0127x over previous
//
#include <hip/hip_runtime.h>

// Problem constants (from reference)
#define Bb   4
#define Ts   512
#define Hh   2048
#define Vv   32000
#define Nn   2048            // B*T
#define BETA 0.1f

// Tiling: block owns 128 rows x 256 cols. BK=32, double-buffered LDS (2x24KB),
// 2-phase schedule: STAGE(next buf) issued before MFMA(cur buf), 1 barrier/step.
#define CHUNKS 125           // 125 * 256 = 32000 = V
#define NPC    250           // partial sets per row = CHUNKS * 2 (per wave-column half)
#define NT     64            // K steps = Hh/32

typedef _Float16 h8  __attribute__((ext_vector_type(8)));
typedef _Float16 h4v __attribute__((ext_vector_type(4)));
typedef float    f4  __attribute__((ext_vector_type(4)));

// LDS rows are 32 halfs (64B). XOR-swizzle spreads the 4 16B slots of a row
// across banks keyed by (row>>1)&3 -> column-slice ds_read_b128 is <=2-way
// (free, m136). Staging inverse (linear gload_lds dest): k_src=((l&3)^((l>>3)&3))<<3.
__device__ __forceinline__ int swz32(int row, int k) {
    return row * 32 + (k ^ (((row >> 1) & 3) << 3));
}

template<bool FAST>
__global__ __launch_bounds__(256, 2) void grpo_gemm(
    const float* __restrict__ inP, const float* __restrict__ wP, const float* __restrict__ bP,
    const float* __restrict__ inR, const float* __restrict__ wR, const float* __restrict__ bR,
    const _Float16* __restrict__ inP16, const _Float16* __restrict__ wP16,
    const _Float16* __restrict__ inR16, const _Float16* __restrict__ wR16,
    float* __restrict__ Pm, float* __restrict__ Ps, int* __restrict__ Pa,
    float* __restrict__ Rm, float* __restrict__ Rs, float* __restrict__ Ra)
{
    // per buffer: A[128][32] = 4096 halfs, W[256][32] = 8192 halfs -> 12288 (24KB)
    __shared__ __align__(16) unsigned short lds[24576];   // 2 buffers = 48KB

    // XCD-aware swizzle (T1): 2000 = 8*250, bijective. Blocks with same bid%8
    // (one XCD) get a contiguous g-range -> each chunk's 16 row-blocks co-XCD.
    const int bid   = blockIdx.x;
    const int g     = (bid & 7) * 250 + (bid >> 3);
    const int chunk = g >> 4;               // 0..124
    const int rowT  = g & 15;               // 0..15

    const int tid   = threadIdx.x;
    const int lane  = tid & 63;
    const int wid   = tid >> 6;
    const int wr    = wid >> 1;             // wave row half (0/1)
    const int wc    = wid & 1;              // wave col half (0/1)
    const int lr    = lane & 15;
    const int lk    = lane >> 4;

    const int rowBase = rowT * 128;
    const int colBase = chunk * 256;

    f4 acc[2][4][4];                        // [vtile][m][n], statically indexed

    // swizzle key for frag reads is lane-only: ((row>>1)&3) == ((lr>>1)&3) for all frags
    const int rdk = ((lr >> 1) & 3) << 3;

    // 32 MFMAs from one staged buffer
    auto mma = [&](const int bufBase) {
        h8 af[4];
        #pragma unroll
        for (int m = 0; m < 4; m++)
            af[m] = *reinterpret_cast<const h8*>(&lds[bufBase + (wr * 64 + m * 16 + lr) * 32 + (lk * 8 ^ rdk)]);
        __builtin_amdgcn_s_setprio(1);
        #pragma unroll
        for (int vt = 0; vt < 2; ++vt) {
            h8 wf[4];
            #pragma unroll
            for (int n = 0; n < 4; n++)
                wf[n] = *reinterpret_cast<const h8*>(
                    &lds[bufBase + 4096 + (vt * 128 + wc * 64 + n * 16 + lr) * 32 + (lk * 8 ^ rdk)]);
            #pragma unroll
            for (int m = 0; m < 4; m++)
                #pragma unroll
                for (int n = 0; n < 4; n++)
                    acc[vt][m][n] = __builtin_amdgcn_mfma_f32_16x16x32_f16(af[m], wf[n], acc[vt][m][n], 0, 0, 0);
        }
        __builtin_amdgcn_s_setprio(0);
    };

    // ---- one full pass (policy or ref): 128x256 logits into acc ----
    auto pass_gemm = [&](const float* __restrict__ IN, const float* __restrict__ W,
                         const _Float16* __restrict__ IN16, const _Float16* __restrict__ W16) {
        #pragma unroll
        for (int vt = 0; vt < 2; ++vt)
            #pragma unroll
            for (int m = 0; m < 4; m++)
                #pragma unroll
                for (int n = 0; n < 4; n++) { f4 z = {0.f, 0.f, 0.f, 0.f}; acc[vt][m][n] = z; }

        if constexpr (FAST) {
            // per wave: 6 x 1KB chunks; chunk c<8 = A rows, c>=8 = W rows.
            // LDS dest offset = c*512 (A region [0,4096), W region [4096,12288)).
            const int rsub = lane >> 2;                               // row in 16-row chunk
            const int ksrc = ((lane & 3) ^ ((lane >> 3) & 3)) << 3;   // inverse-swizzled k
            const _Float16* src[6]; int dOff[6];
            #pragma unroll
            for (int i = 0; i < 6; i++) {
                const int c = wid * 6 + i;
                dOff[i] = c * 512;
                src[i] = (c < 8)
                    ? IN16 + (size_t)(rowBase + c * 16 + rsub) * Hh + ksrc
                    : W16  + (size_t)(colBase + (c - 8) * 16 + rsub) * Hh + ksrc;
            }
            auto stage = [&](const int bufBase, const int kt) {
                #pragma unroll
                for (int i = 0; i < 6; i++)
                    __builtin_amdgcn_global_load_lds(
                        (const __attribute__((address_space(1))) void*)(src[i] + kt * 32),
                        (__attribute__((address_space(3))) void*)&lds[bufBase + dOff[i]], 16, 0, 0);
            };
            stage(0, 0);
            __syncthreads();                      // drains vmcnt: buf0 ready
            for (int kt = 0; kt < NT; kt += 2) {
                stage(12288, kt + 1);             // prefetch next into buf1
                mma(0);                           // compute buf0
                __syncthreads();                  // buf1 staged, buf0 reads done
                if (kt + 2 < NT) stage(0, kt + 2);
                mma(12288);
                __syncthreads();
            }
        } else {
            // fallback: fp32 global -> cvt -> ds_write, single buffer, 2 barriers/step
            for (int kt = 0; kt < NT; ++kt) {
                __syncthreads();
                #pragma unroll
                for (int i = 0; i < 12; i++) {        // 3072 groups of 4 halfs
                    const int gq = tid + i * 256;
                    int dst; const float* s;
                    if (gq < 1024) { const int r = gq >> 3, kk = (gq & 7) << 2;
                        s = IN + (size_t)(rowBase + r) * Hh + kt * 32 + kk; dst = swz32(r, kk); }
                    else { const int gw = gq - 1024, r = gw >> 3, kk = (gw & 7) << 2;
                        s = W + (size_t)(colBase + r) * Hh + kt * 32 + kk; dst = 4096 + swz32(r, kk); }
                    const float4 v = *reinterpret_cast<const float4*>(s);
                    h4v h; h[0] = (_Float16)v.x; h[1] = (_Float16)v.y; h[2] = (_Float16)v.z; h[3] = (_Float16)v.w;
                    *reinterpret_cast<h4v*>(&lds[dst]) = h;
                }
                __syncthreads();
                mma(0);
            }
        }
    };

    // ================= policy pass: online max/argmax/sumexp =================
    // C/D layout (m89-verified): col = lane&15, row = (lane>>4)*4 + reg.
    float sM[16], sS[16]; int sA[16];
    #pragma unroll
    for (int s = 0; s < 16; s++) { sM[s] = -__builtin_inff(); sS[s] = 0.f; sA[s] = 0x7fffffff; }

    pass_gemm(inP, wP, inP16, wP16);
    #pragma unroll
    for (int vt = 0; vt < 2; ++vt) {
        float bn[4];
        #pragma unroll
        for (int n = 0; n < 4; n++) bn[n] = bP[colBase + vt * 128 + wc * 64 + n * 16 + lr];
        #pragma unroll
        for (int m = 0; m < 4; m++)
            #pragma unroll
            for (int n = 0; n < 4; n++) {
                const int vg = colBase + vt * 128 + wc * 64 + n * 16 + lr;
                #pragma unroll
                for (int r = 0; r < 4; r++) {
                    const int s = m * 4 + r;
                    const float v = acc[vt][m][n][r] + bn[n];
                    if (v > sM[s]) { sS[s] = sS[s] * __expf(sM[s] - v) + 1.f; sM[s] = v; sA[s] = vg; }
                    else           { sS[s] += __expf(v - sM[s]); }
                }
            }
    }

    int aWin[16];
    #pragma unroll
    for (int s = 0; s < 16; s++) {
        float M = sM[s], S = sS[s]; int A = sA[s];
        #pragma unroll
        for (int d = 1; d < 16; d <<= 1) {
            float oM = __shfl_xor(M, d), oS = __shfl_xor(S, d); int oA = __shfl_xor(A, d);
            if (oM > M || (oM == M && oA < A)) { S = S * __expf(M - oM) + oS; M = oM; A = oA; }
            else                               { S += oS * __expf(oM - M); }
        }
        aWin[s] = A;
        if (lr == 0) {
            const int row = rowBase + wr * 64 + (s >> 2) * 16 + lk * 4 + (s & 3);
            const size_t id = (size_t)row * NPC + (chunk * 2 + wc);   // [row][pc] layout
            Pm[id] = M; Ps[id] = S; Pa[id] = A;
        }
    }

    // ================= ref pass: lse stats + ref logit at policy argmax =================
    float rM[16], rS[16], rT[16];
    #pragma unroll
    for (int s = 0; s < 16; s++) { rM[s] = -__builtin_inff(); rS[s] = 0.f; rT[s] = -1e30f; }

    pass_gemm(inR, wR, inR16, wR16);
    #pragma unroll
    for (int vt = 0; vt < 2; ++vt) {
        float bn[4];
        #pragma unroll
        for (int n = 0; n < 4; n++) bn[n] = bR[colBase + vt * 128 + wc * 64 + n * 16 + lr];
        #pragma unroll
        for (int m = 0; m < 4; m++)
            #pragma unroll
            for (int n = 0; n < 4; n++) {
                const int vg = colBase + vt * 128 + wc * 64 + n * 16 + lr;
                #pragma unroll
                for (int r = 0; r < 4; r++) {
                    const int s = m * 4 + r;
                    const float v = acc[vt][m][n][r] + bn[n];
                    if (v > rM[s]) { rS[s] = rS[s] * __expf(rM[s] - v) + 1.f; rM[s] = v; }
                    else           { rS[s] += __expf(v - rM[s]); }
                    if (vg == aWin[s]) rT[s] = v;
                }
            }
    }

    #pragma unroll
    for (int s = 0; s < 16; s++) {
        float M = rM[s], S = rS[s], Tv = rT[s];
        #pragma unroll
        for (int d = 1; d < 16; d <<= 1) {
            float oM = __shfl_xor(M, d), oS = __shfl_xor(S, d), oT = __shfl_xor(Tv, d);
            if (oM > M) { S = S * __expf(M - oM) + oS; M = oM; }
            else        { S += oS * __expf(oM - M); }
            Tv = fmaxf(Tv, oT);
        }
        if (lr == 0) {
            const int row = rowBase + wr * 64 + (s >> 2) * 16 + lk * 4 + (s & 3);
            const size_t id = (size_t)row * NPC + (chunk * 2 + wc);
            Rm[id] = M; Rs[id] = S; Ra[id] = Tv;
        }
    }
}

// fp32 -> f16 bulk convert, all four arrays in one launch (blockIdx.y selects)
__global__ __launch_bounds__(256) void cvt_all(
    const float* __restrict__ s0, _Float16* __restrict__ d0, size_t n0,
    const float* __restrict__ s1, _Float16* __restrict__ d1, size_t n1,
    const float* __restrict__ s2, _Float16* __restrict__ d2, size_t n2,
    const float* __restrict__ s3, _Float16* __restrict__ d3, size_t n3)
{
    const float* s; _Float16* d; size_t n;
    switch (blockIdx.y) {
        case 0: s = s0; d = d0; n = n0; break;
        case 1: s = s1; d = d1; n = n1; break;
        case 2: s = s2; d = d2; n = n2; break;
        default: s = s3; d = d3; n = n3; break;
    }
    size_t i = ((size_t)blockIdx.x * 256 + threadIdx.x) * 8;
    const size_t stride = (size_t)gridDim.x * 256 * 8;
    for (; i < n; i += stride) {
        const float4 a = *reinterpret_cast<const float4*>(s + i);
        const float4 b = *reinterpret_cast<const float4*>(s + i + 4);
        h8 h;
        h[0] = (_Float16)a.x; h[1] = (_Float16)a.y; h[2] = (_Float16)a.z; h[3] = (_Float16)a.w;
        h[4] = (_Float16)b.x; h[5] = (_Float16)b.y; h[6] = (_Float16)b.z; h[7] = (_Float16)b.w;
        *reinterpret_cast<h8*>(d + i) = h;
    }
}

// One block (1 wave) per row: parallel merge of 250 partials, butterfly reduce.
__global__ __launch_bounds__(64) void grpo_combine(
    const float* __restrict__ Pm, const float* __restrict__ Ps, const int* __restrict__ Pa,
    const float* __restrict__ Rm, const float* __restrict__ Rs, const float* __restrict__ Ra,
    const float* __restrict__ amask, const float* __restrict__ rewards,
    float* __restrict__ rowNum)
{
    const int row = blockIdx.x;
    const int t   = threadIdx.x;
    const size_t base = (size_t)row * NPC;

    float M = -__builtin_inff(), S = 0.f; int A = 0x7fffffff; float Rv = -1e30f;
    float RM = -__builtin_inff(), RS = 0.f;
    #pragma unroll
    for (int j = 0; j < 4; j++) {
        const int pc = t + j * 64;                 // coalesced across lanes
        if (pc < NPC) {
            const float m = Pm[base + pc], s = Ps[base + pc], rv = Ra[base + pc];
            const int   a = Pa[base + pc];
            if (m > M || (m == M && a < A)) { S = s + S * __expf(M - m); M = m; A = a; Rv = rv; }
            else                            { S += s * __expf(m - M); }
            const float rm = Rm[base + pc], rs = Rs[base + pc];
            if (rm > RM) { RS = rs + RS * __expf(RM - rm); RM = rm; }
            else         { RS += rs * __expf(rm - RM); }
        }
    }
    #pragma unroll
    for (int d = 1; d < 64; d <<= 1) {
        const float oM = __shfl_xor(M, d), oS = __shfl_xor(S, d), oRv = __shfl_xor(Rv, d);
        const int   oA = __shfl_xor(A, d);
        if (oM > M || (oM == M && oA < A)) { S = oS + S * __expf(M - oM); M = oM; A = oA; Rv = oRv; }
        else                               { S += oS * __expf(oM - M); }
        const float orM = __shfl_xor(RM, d), orS = __shfl_xor(RS, d);
        if (orM > RM) { RS = orS + RS * __expf(RM - orM); RM = orM; }
        else          { RS += orS * __expf(orM - RM); }
    }

    if (t == 0) {
        const float r0 = rewards[0], r1 = rewards[1], r2 = rewards[2], r3 = rewards[3];
        const float mean = 0.25f * (r0 + r1 + r2 + r3);
        const float var  = ((r0 - mean) * (r0 - mean) + (r1 - mean) * (r1 - mean) +
                            (r2 - mean) * (r2 - mean) + (r3 - mean) * (r3 - mean)) * (1.f / 3.f);
        const float inv  = 1.f / (sqrtf(var) + 1e-4f);
        const int   b    = row >> 9;
        const float advb = (b == 0 ? (r0 - mean) : b == 1 ? (r1 - mean) : b == 2 ? (r2 - mean) : (r3 - mean)) * inv;

        const float tok  = -logf(S);               // chosen == argmax
        const float rtok = Rv - (RM + logf(RS));
        const float dd   = rtok - tok;
        const float kl   = expf(dd) - dd - 1.f;
        rowNum[row] = (-advb + BETA * kl) * amask[row];
    }
}

__global__ __launch_bounds__(256) void grpo_final(
    const float* __restrict__ rowNum, const float* __restrict__ amask, float* __restrict__ out)
{
    __shared__ float sn[256], sd[256];
    float n = 0.f, d = 0.f;
    for (int i = threadIdx.x; i < Nn; i += 256) { n += rowNum[i]; d += amask[i]; }
    sn[threadIdx.x] = n; sd[threadIdx.x] = d;
    __syncthreads();
    for (int o = 128; o > 0; o >>= 1) {
        if (threadIdx.x < o) { sn[threadIdx.x] += sn[threadIdx.x + o]; sd[threadIdx.x] += sd[threadIdx.x + o]; }
        __syncthreads();
    }
    if (threadIdx.x == 0) out[0] = sn[0] / fmaxf(sd[0], 1.f);
}

extern "C" void kernel_launch(void* const* d_in, const int* in_sizes, int n_in,
                              void* d_out, int out_size, void* d_ws, size_t ws_size,
                              hipStream_t stream)
{
    (void)in_sizes; (void)n_in; (void)out_size;

    const float* inP = (const float*)d_in[0];   // _input        [N,H]
    const float* wP  = (const float*)d_in[1];   // weight        [V,H]
    const float* am  = (const float*)d_in[2];   // attention_mask[B,T]
    const float* rw  = (const float*)d_in[3];   // rewards       [B]
    const float* bP  = (const float*)d_in[4];   // bias          [V]
    const float* inR = (const float*)d_in[5];   // ref_input     [N,H]
    const float* wR  = (const float*)d_in[6];   // ref_weight    [V,H]
    const float* bR  = (const float*)d_in[7];   // ref_bias      [V]
    float* out = (float*)d_out;

    char* w = (char*)d_ws;
    const size_t arr = (size_t)NPC * Nn * sizeof(float);    // 2,048,000 B
    float* Pm = (float*)w; w += arr;
    float* Ps = (float*)w; w += arr;
    int*   Pa = (int*)  w; w += arr;
    float* Rm = (float*)w; w += arr;
    float* Rs = (float*)w; w += arr;
    float* Ra = (float*)w; w += arr;
    float* rowNum = (float*)w; w += ((size_t)Nn * sizeof(float) + 255) & ~(size_t)255;

    const size_t fA = (size_t)Nn * Hh * sizeof(_Float16);   //   8,388,608 B
    const size_t fW = (size_t)Vv * Hh * sizeof(_Float16);   // 131,072,000 B
    const size_t need = (size_t)(w - (char*)d_ws) + 2 * fA + 2 * fW;   // ~291.5 MB
    const bool fast = (ws_size >= need);

    if (fast) {
        _Float16* inP16 = (_Float16*)w;            w += fA;
        _Float16* inR16 = (_Float16*)w;            w += fA;
        _Float16* wP16  = (_Float16*)w;            w += fW;
        _Float16* wR16  = (_Float16*)w;            w += fW;
        hipLaunchKernelGGL(cvt_all, dim3(2048, 4), dim3(256), 0, stream,
                           inP, inP16, (size_t)Nn * Hh,
                           inR, inR16, (size_t)Nn * Hh,
                           wP,  wP16,  (size_t)Vv * Hh,
                           wR,  wR16,  (size_t)Vv * Hh);
        hipLaunchKernelGGL((grpo_gemm<true>), dim3(16 * CHUNKS), dim3(256), 0, stream,
                           inP, wP, bP, inR, wR, bR, inP16, wP16, inR16, wR16,
                           Pm, Ps, Pa, Rm, Rs, Ra);
    } else {
        hipLaunchKernelGGL((grpo_gemm<false>), dim3(16 * CHUNKS), dim3(256), 0, stream,
                           inP, wP, bP, inR, wR, bR,
                           (const _Float16*)nullptr, (const _Float16*)nullptr,
                           (const _Float16*)nullptr, (const _Float16*)nullptr,
                           Pm, Ps, Pa, Rm, Rs, Ra);
    }

    hipLaunchKernelGGL(grpo_combine, dim3(Nn), dim3(64), 0, stream,
                       Pm, Ps, Pa, Rm, Rs, Ra, am, rw, rowNum);
    hipLaunchKernelGGL(grpo_final, dim3(1), dim3(256), 0, stream, rowNum, am, out);
}